// Round 5
// baseline (431.926 us; speedup 1.0000x reference)
//
#include <hip/hip_runtime.h>
#include <cstdint>
#include <math.h>

#define B_ 8
#define L_ 2048
#define D_ 2048
#define R_ 256

typedef __bf16 bf16x8 __attribute__((ext_vector_type(8)));
typedef float f32x4 __attribute__((ext_vector_type(4)));

__device__ __forceinline__ unsigned short f2bf(float f) {
    uint32_t u = __builtin_bit_cast(uint32_t, f);
    u += 0x7FFFu + ((u >> 16) & 1u);
    return (unsigned short)(u >> 16);
}

#define GLDS16(gp, lp)                                                          \
    __builtin_amdgcn_global_load_lds(                                           \
        (const __attribute__((address_space(1))) void*)(gp),                    \
        (__attribute__((address_space(3))) void*)(lp), 16, 0, 0)

// ---------------------------------------------------------------------------
// Kernel 1: LayerNorm (fp32 -> bf16) + feat via closed form, ONE reduction:
// feat = mean(n) = (rstd*(Sxg - mean*Sg) + Sb) / D
// ---------------------------------------------------------------------------
__global__ __launch_bounds__(256) void ln_kernel(
    const float* __restrict__ x, const float* __restrict__ gamma,
    const float* __restrict__ beta, unsigned short* __restrict__ xn,
    float* __restrict__ feat)
{
    const int row  = blockIdx.x;
    const int t    = threadIdx.x;
    const int w    = t >> 6, lane = t & 63;
    const float4* x4 = (const float4*)(x + (size_t)row * D_);
    const float4* g4 = (const float4*)gamma;
    const float4* b4 = (const float4*)beta;
    float4 a  = x4[t];
    float4 b  = x4[t + 256];
    float4 g0 = g4[t], g1 = g4[t + 256];
    float4 e0 = b4[t], e1 = b4[t + 256];

    float s   = a.x + a.y + a.z + a.w + b.x + b.y + b.z + b.w;
    float sq  = a.x*a.x + a.y*a.y + a.z*a.z + a.w*a.w
              + b.x*b.x + b.y*b.y + b.z*b.z + b.w*b.w;
    float sxg = a.x*g0.x + a.y*g0.y + a.z*g0.z + a.w*g0.w
              + b.x*g1.x + b.y*g1.y + b.z*g1.z + b.w*g1.w;
    float sg  = g0.x + g0.y + g0.z + g0.w + g1.x + g1.y + g1.z + g1.w;
    float sb  = e0.x + e0.y + e0.z + e0.w + e1.x + e1.y + e1.z + e1.w;

    __shared__ float red[20];
#pragma unroll
    for (int o = 32; o; o >>= 1) {
        s   += __shfl_down(s, o);
        sq  += __shfl_down(sq, o);
        sxg += __shfl_down(sxg, o);
        sg  += __shfl_down(sg, o);
        sb  += __shfl_down(sb, o);
    }
    if (lane == 0) {
        red[w] = s; red[4+w] = sq; red[8+w] = sxg; red[12+w] = sg; red[16+w] = sb;
    }
    __syncthreads();
    float S    = red[0] + red[1] + red[2] + red[3];
    float SQ   = red[4] + red[5] + red[6] + red[7];
    float SXG  = red[8] + red[9] + red[10] + red[11];
    float SG   = red[12] + red[13] + red[14] + red[15];
    float SB   = red[16] + red[17] + red[18] + red[19];
    float mean = S * (1.0f / D_);
    float var  = SQ * (1.0f / D_) - mean * mean;
    float rstd = rsqrtf(var + 1e-5f);
    if (t == 0)
        feat[row] = (rstd * (SXG - mean * SG) + SB) * (1.0f / D_);

    float n[8];
    n[0] = (a.x - mean) * rstd * g0.x + e0.x;
    n[1] = (a.y - mean) * rstd * g0.y + e0.y;
    n[2] = (a.z - mean) * rstd * g0.z + e0.z;
    n[3] = (a.w - mean) * rstd * g0.w + e0.w;
    n[4] = (b.x - mean) * rstd * g1.x + e1.x;
    n[5] = (b.y - mean) * rstd * g1.y + e1.y;
    n[6] = (b.z - mean) * rstd * g1.z + e1.z;
    n[7] = (b.w - mean) * rstd * g1.w + e1.w;

    ushort4 o0, o1;
    o0.x = f2bf(n[0]); o0.y = f2bf(n[1]); o0.z = f2bf(n[2]); o0.w = f2bf(n[3]);
    o1.x = f2bf(n[4]); o1.y = f2bf(n[5]); o1.z = f2bf(n[6]); o1.w = f2bf(n[7]);
    ((ushort4*)(xn + (size_t)row * D_))[t]       = o0;
    ((ushort4*)(xn + (size_t)row * D_))[t + 256] = o1;
}

// ---------------------------------------------------------------------------
// prep1: block-range dispatch, ALL loads coalesced or uniform
//   blocks [0,32):     P (DxR f32) -> PT (RxD bf16)  [LDS transpose]
//   blocks [32,288):   C[r][d] = sum_s toep[r-s+127]*Wq[s][d]
//                      block = (r-tile of 8) x (d-chunk of 256); thread = d;
//                      Wq row reads COALESCED; toep in LDS; 8 accs/thread
//   blocks [288,2336): gs[l] = g(l)*scale[l], bgs[l] = bq[l]*gs[l]
// ---------------------------------------------------------------------------
__global__ __launch_bounds__(256) void prep1_kernel(
    const float* __restrict__ P, unsigned short* __restrict__ PT,
    const float* __restrict__ toep, const float* __restrict__ Wq,
    float* __restrict__ C,
    const float* __restrict__ phi_bias, const float* __restrict__ phi_w,
    const float* __restrict__ feat, const float* __restrict__ bq,
    const float* __restrict__ g_logit, const int* __restrict__ step,
    float* __restrict__ gs, float* __restrict__ bgs)
{
    __shared__ __align__(16) char smem[32768];
    const int bid = blockIdx.x;
    const int t   = threadIdx.x;

    if (bid < 32) {
        // ---- PT transpose ----
        unsigned short* sT = (unsigned short*)smem;   // 64*256 ushort = 32 KB
        const int k0 = bid * 64;
#pragma unroll 8
        for (int j = 0; j < 64; j++)
            sT[j * 256 + t] = f2bf(P[(size_t)(k0 + j) * R_ + t]);
        __syncthreads();
#pragma unroll
        for (int c = 0; c < 16; c++) {
            ushort4 v;
            v.x = sT[(c * 4 + 0) * 256 + t];
            v.y = sT[(c * 4 + 1) * 256 + t];
            v.z = sT[(c * 4 + 2) * 256 + t];
            v.w = sT[(c * 4 + 3) * 256 + t];
            *(ushort4*)(PT + (size_t)t * D_ + k0 + c * 4) = v;
        }
    } else if (bid < 288) {
        // ---- C = Toeplitz(toep) x Wq, coalesced over d ----
        float* toepLds = (float*)smem;                // 255 floats
        const int cid = bid - 32;                     // 0..255
        const int r0  = (cid >> 3) * 8;               // r-tile base
        const int d   = (cid & 7) * 256 + t;          // this thread's column
        if (t < 255) toepLds[t] = toep[t];
        __syncthreads();
        float acc[8] = {};
#pragma unroll 4
        for (int s = 0; s < 256; s++) {
            float wv = Wq[(size_t)s * D_ + d];        // coalesced across t
#pragma unroll
            for (int ri = 0; ri < 8; ri++) {
                int idx = r0 + ri - s + 127;
                if ((unsigned)idx < 255u)
                    acc[ri] += toepLds[idx] * wv;
            }
        }
#pragma unroll
        for (int ri = 0; ri < 8; ri++)
            C[(size_t)(r0 + ri) * D_ + d] = acc[ri];  // coalesced across t
    } else {
        // ---- scale ----
        float* red = (float*)smem;                    // 12 floats
        const int l = bid - 288;
        const int k = t;
        const int w = k >> 6, lane = k & 63;
        float arg = 3.14159265358979323846f * ((float)l + 0.5f) * (float)k * (1.0f / L_);
        float cv = cosf(arg);
        float pb = phi_bias[(size_t)l * R_ + k];
        float pw = phi_w[k];
#pragma unroll
        for (int o = 32; o; o >>= 1) {
            cv += __shfl_down(cv, o);
            pb += __shfl_down(pb, o);
            pw += __shfl_down(pw, o);
        }
        if (lane == 0) { red[w] = cv; red[4 + w] = pb; red[8 + w] = pw; }
        __syncthreads();
        if (k == 0) {
            float cs  = red[0] + red[1] + red[2] + red[3];
            float pbs = red[4] + red[5] + red[6] + red[7];
            float pws = red[8] + red[9] + red[10] + red[11];
            float fb = 0.f;
            for (int b = 0; b < B_; b++) fb += feat[(size_t)b * L_ + l];
            fb *= (1.0f / B_);
            float det = fminf((float)step[0] / 2000.0f, 1.0f);
            float sc  = (det * cs + pbs + fb * pws) * (1.0f / R_);
            float gl  = g_logit[l >> 10];
            float gg  = 1.0f / (1.0f + expf(-gl));
            gs[l]  = gg * sc;
            bgs[l] = bq[l] * gg * sc;
        }
    }
}

// ---------------------------------------------------------------------------
// prep2: WT[d][q] = sum_r dlt[r][q] * C[r][d]
// 1024 blocks, d0 = bid*2; dlt row reads coalesced (thread=q), C reads
// block-uniform (scalar cache); unroll 8 -> 8 loads in flight.
// ---------------------------------------------------------------------------
__global__ __launch_bounds__(256) void prep2_kernel(
    const float* __restrict__ dlt, const float* __restrict__ C,
    unsigned short* __restrict__ WT)
{
    const int d0 = blockIdx.x * 2;
    const int q  = threadIdx.x;
    float a0 = 0.f, a1 = 0.f;
#pragma unroll 8
    for (int r = 0; r < 256; r++) {
        float dv = dlt[(size_t)r * R_ + q];           // coalesced across q
        const float* cr = C + (size_t)r * D_ + d0;    // uniform -> s_load
        a0 += dv * cr[0];
        a1 += dv * cr[1];
    }
    WT[(size_t)(d0 + 0) * R_ + q] = f2bf(a0);
    WT[(size_t)(d0 + 1) * R_ + q] = f2bf(a1);
}

// ---------------------------------------------------------------------------
// GEMM1 (m97 structure): u(16384x256 bf16) = xn @ P  (B transposed: PT, RxD)
// BM=128, BN=128, BK=64; 4 waves x (64x64) sub-tiles; double-buffered GLDS16
// prefetch-before-compute; 64KB LDS, 2 blocks/CU. grid (2, 128).
// ---------------------------------------------------------------------------
__global__ __launch_bounds__(256, 2) void gemm1_kernel(
    const unsigned short* __restrict__ A,   // xn, lda=2048
    const unsigned short* __restrict__ BT,  // PT,  ldb=2048
    unsigned short* __restrict__ U)         // 16384x256
{
    __shared__ __align__(16) unsigned short sA[2][2][128 * 32];
    __shared__ __align__(16) unsigned short sB[2][2][128 * 32];
    const int tid  = threadIdx.x;
    const int n0   = blockIdx.x * 128;
    const int m0   = blockIdx.y * 128;
    const int w    = tid >> 6, lane = tid & 63;
    const int quad = lane >> 4, m16 = lane & 15;
    const int wm   = (w >> 1) * 64, wn = (w & 1) * 64;
    const int ra   = tid >> 2, sa = tid & 3;

    const unsigned short* apb = A  + (size_t)(m0 + ra) * 2048 + sa * 8;
    const unsigned short* bpb = BT + (size_t)(n0 + ra) * 2048 + sa * 8;

    f32x4 acc[4][4] = {};

#define G1_STAGE(buf, kc)                                                       \
    do {                                                                        \
        _Pragma("unroll")                                                       \
        for (int h = 0; h < 2; h++) {                                           \
            GLDS16(apb + (kc) + h * 32,              &sA[buf][h][tid * 8]);     \
            GLDS16(apb + (kc) + h * 32 + 64 * 2048,  &sA[buf][h][2048 + tid * 8]); \
            GLDS16(bpb + (kc) + h * 32,              &sB[buf][h][tid * 8]);     \
            GLDS16(bpb + (kc) + h * 32 + 64 * 2048,  &sB[buf][h][2048 + tid * 8]); \
        }                                                                       \
    } while (0)

    G1_STAGE(0, 0);
    __syncthreads();

    int cur = 0;
    for (int kc = 0; kc < 2048; kc += 64) {
        if (kc + 64 < 2048) G1_STAGE(cur ^ 1, kc + 64);
#pragma unroll
        for (int h = 0; h < 2; h++) {
            bf16x8 af[4], bf[4];
#pragma unroll
            for (int i = 0; i < 4; i++)
                af[i] = *(const bf16x8*)(&sA[cur][h][(wm + i * 16 + m16) * 32 + quad * 8]);
#pragma unroll
            for (int j = 0; j < 4; j++)
                bf[j] = *(const bf16x8*)(&sB[cur][h][(wn + j * 16 + m16) * 32 + quad * 8]);
#pragma unroll
            for (int i = 0; i < 4; i++)
#pragma unroll
                for (int j = 0; j < 4; j++)
                    acc[i][j] = __builtin_amdgcn_mfma_f32_16x16x32_bf16(
                        af[i], bf[j], acc[i][j], 0, 0, 0);
        }
        __syncthreads();
        cur ^= 1;
    }
#undef G1_STAGE

#pragma unroll
    for (int i = 0; i < 4; i++)
#pragma unroll
        for (int j = 0; j < 4; j++) {
            int col = n0 + wn + j * 16 + m16;
#pragma unroll
            for (int r = 0; r < 4; r++) {
                int row = m0 + wm + i * 16 + quad * 4 + r;
                U[(size_t)row * 256 + col] = f2bf(acc[i][j][r]);
            }
        }
}

// ---------------------------------------------------------------------------
// GEMM2: out(16384x2048 f32) = u @ W_eff (via WT), epilogue *gs[col]+bgs[col]
// BM=128, BN=128, BK=32 (8 K-steps), double-buffered. 32KB LDS, 3 blocks/CU.
// ---------------------------------------------------------------------------
__global__ __launch_bounds__(256, 3) void gemm2_kernel(
    const unsigned short* __restrict__ A,   // u,  lda=256
    const unsigned short* __restrict__ BT,  // WT, ldb=256
    const float* __restrict__ gs, const float* __restrict__ bgs,
    float* __restrict__ out)
{
    __shared__ __align__(16) unsigned short sA[2][128 * 32];
    __shared__ __align__(16) unsigned short sB[2][128 * 32];
    const int tid  = threadIdx.x;
    const int n0   = blockIdx.x * 128;
    const int m0   = blockIdx.y * 128;
    const int w    = tid >> 6, lane = tid & 63;
    const int quad = lane >> 4, m16 = lane & 15;
    const int wm   = (w >> 1) * 64, wn = (w & 1) * 64;
    const int ra   = tid >> 2, sa = tid & 3;

    const unsigned short* apb0 = A  + (size_t)(m0 + ra) * 256 + sa * 8;
    const unsigned short* apb1 = apb0 + (size_t)64 * 256;
    const unsigned short* bpb0 = BT + (size_t)(n0 + ra) * 256 + sa * 8;
    const unsigned short* bpb1 = bpb0 + (size_t)64 * 256;

    float gv[4], bv[4];
#pragma unroll
    for (int j = 0; j < 4; j++) {
        int col = n0 + wn + j * 16 + m16;
        gv[j] = gs[col];
        bv[j] = bgs[col];
    }

    f32x4 acc[4][4] = {};

#define G2_STAGE(buf, kc)                                      \
    do {                                                       \
        GLDS16(apb0 + (kc), &sA[buf][tid * 8]);                \
        GLDS16(apb1 + (kc), &sA[buf][(256 + tid) * 8]);        \
        GLDS16(bpb0 + (kc), &sB[buf][tid * 8]);                \
        GLDS16(bpb1 + (kc), &sB[buf][(256 + tid) * 8]);        \
    } while (0)

    G2_STAGE(0, 0);
    __syncthreads();

    int cur = 0;
    for (int kc = 0; kc < 256; kc += 32) {
        if (kc + 32 < 256) G2_STAGE(cur ^ 1, kc + 32);
        bf16x8 af[4], bf[4];
#pragma unroll
        for (int i = 0; i < 4; i++)
            af[i] = *(const bf16x8*)(&sA[cur][(wm + i * 16 + m16) * 32 + quad * 8]);
#pragma unroll
        for (int j = 0; j < 4; j++)
            bf[j] = *(const bf16x8*)(&sB[cur][(wn + j * 16 + m16) * 32 + quad * 8]);
#pragma unroll
        for (int i = 0; i < 4; i++)
#pragma unroll
            for (int j = 0; j < 4; j++)
                acc[i][j] = __builtin_amdgcn_mfma_f32_16x16x32_bf16(
                    af[i], bf[j], acc[i][j], 0, 0, 0);
        __syncthreads();
        cur ^= 1;
    }
#undef G2_STAGE

#pragma unroll
    for (int i = 0; i < 4; i++)
#pragma unroll
        for (int r = 0; r < 4; r++) {
            int row = m0 + wm + i * 16 + quad * 4 + r;
            float* op = out + (size_t)row * 2048 + n0 + wn;
#pragma unroll
            for (int j = 0; j < 4; j++)
                op[j * 16 + m16] = acc[i][j][r] * gv[j] + bv[j];
        }
}

// ---------------------------------------------------------------------------
extern "C" void kernel_launch(void* const* d_in, const int* in_sizes, int n_in,
                              void* d_out, int out_size, void* d_ws, size_t ws_size,
                              hipStream_t stream)
{
    const float* x        = (const float*)d_in[0];
    const float* ln_gamma = (const float*)d_in[1];
    const float* ln_beta  = (const float*)d_in[2];
    const float* P        = (const float*)d_in[3];
    const float* dlt      = (const float*)d_in[4];
    const float* phi_w    = (const float*)d_in[5];
    const float* phi_bias = (const float*)d_in[6];
    const float* toep     = (const float*)d_in[7];
    const float* Wq       = (const float*)d_in[8];
    const float* bq       = (const float*)d_in[9];
    const float* g_logit  = (const float*)d_in[10];
    const int*   step     = (const int*)d_in[11];
    float* out = (float*)d_out;

    char* w = (char*)d_ws;
    unsigned short* xn  = (unsigned short*)(w);                    // 67,108,864 B
    unsigned short* u   = (unsigned short*)(w + 67108864);         //  8,388,608 B
    unsigned short* PT  = (unsigned short*)(w + 75497472);         //  1,048,576 B
    unsigned short* WT  = (unsigned short*)(w + 76546048);         //  1,048,576 B
    float*          C   = (float*)(w + 77594624);                  //  2,097,152 B
    float*          feat= (float*)(w + 79691776);                  //     65,536 B
    float*          gs  = (float*)(w + 79757312);                  //      8,192 B
    float*          bgs = (float*)(w + 79765504);                  //      8,192 B

    ln_kernel<<<dim3(B_ * L_), dim3(256), 0, stream>>>(x, ln_gamma, ln_beta, xn, feat);
    prep1_kernel<<<dim3(2336), dim3(256), 0, stream>>>(P, PT, toep, Wq, C,
                                                       phi_bias, phi_w, feat, bq,
                                                       g_logit, step, gs, bgs);
    prep2_kernel<<<dim3(1024), dim3(256), 0, stream>>>(dlt, C, WT);
    gemm1_kernel<<<dim3(2, 128), dim3(256), 0, stream>>>(xn, PT, u);
    gemm2_kernel<<<dim3(16, 128), dim3(256), 0, stream>>>(u, WT, gs, bgs, out);
}

// Round 6
// 373.412 us; speedup vs baseline: 1.1567x; 1.1567x over previous
//
#include <hip/hip_runtime.h>
#include <cstdint>
#include <math.h>

#define B_ 8
#define L_ 2048
#define D_ 2048
#define R_ 256

typedef __bf16 bf16x8 __attribute__((ext_vector_type(8)));
typedef float f32x4 __attribute__((ext_vector_type(4)));

__device__ __forceinline__ unsigned short f2bf(float f) {
    uint32_t u = __builtin_bit_cast(uint32_t, f);
    u += 0x7FFFu + ((u >> 16) & 1u);
    return (unsigned short)(u >> 16);
}

#define GLDS16(gp, lp)                                                          \
    __builtin_amdgcn_global_load_lds(                                           \
        (const __attribute__((address_space(1))) void*)(gp),                    \
        (__attribute__((address_space(3))) void*)(lp), 16, 0, 0)

// ---------------------------------------------------------------------------
// Kernel 1: LayerNorm (fp32 -> bf16) + feat via closed form, ONE reduction:
// feat = mean(n) = (rstd*(Sxg - mean*Sg) + Sb) / D
// ---------------------------------------------------------------------------
__global__ __launch_bounds__(256) void ln_kernel(
    const float* __restrict__ x, const float* __restrict__ gamma,
    const float* __restrict__ beta, unsigned short* __restrict__ xn,
    float* __restrict__ feat)
{
    const int row  = blockIdx.x;
    const int t    = threadIdx.x;
    const int w    = t >> 6, lane = t & 63;
    const float4* x4 = (const float4*)(x + (size_t)row * D_);
    const float4* g4 = (const float4*)gamma;
    const float4* b4 = (const float4*)beta;
    float4 a  = x4[t];
    float4 b  = x4[t + 256];
    float4 g0 = g4[t], g1 = g4[t + 256];
    float4 e0 = b4[t], e1 = b4[t + 256];

    float s   = a.x + a.y + a.z + a.w + b.x + b.y + b.z + b.w;
    float sq  = a.x*a.x + a.y*a.y + a.z*a.z + a.w*a.w
              + b.x*b.x + b.y*b.y + b.z*b.z + b.w*b.w;
    float sxg = a.x*g0.x + a.y*g0.y + a.z*g0.z + a.w*g0.w
              + b.x*g1.x + b.y*g1.y + b.z*g1.z + b.w*g1.w;
    float sg  = g0.x + g0.y + g0.z + g0.w + g1.x + g1.y + g1.z + g1.w;
    float sb  = e0.x + e0.y + e0.z + e0.w + e1.x + e1.y + e1.z + e1.w;

    __shared__ float red[20];
#pragma unroll
    for (int o = 32; o; o >>= 1) {
        s   += __shfl_down(s, o);
        sq  += __shfl_down(sq, o);
        sxg += __shfl_down(sxg, o);
        sg  += __shfl_down(sg, o);
        sb  += __shfl_down(sb, o);
    }
    if (lane == 0) {
        red[w] = s; red[4+w] = sq; red[8+w] = sxg; red[12+w] = sg; red[16+w] = sb;
    }
    __syncthreads();
    float S    = red[0] + red[1] + red[2] + red[3];
    float SQ   = red[4] + red[5] + red[6] + red[7];
    float SXG  = red[8] + red[9] + red[10] + red[11];
    float SG   = red[12] + red[13] + red[14] + red[15];
    float SB   = red[16] + red[17] + red[18] + red[19];
    float mean = S * (1.0f / D_);
    float var  = SQ * (1.0f / D_) - mean * mean;
    float rstd = rsqrtf(var + 1e-5f);
    if (t == 0)
        feat[row] = (rstd * (SXG - mean * SG) + SB) * (1.0f / D_);

    float n[8];
    n[0] = (a.x - mean) * rstd * g0.x + e0.x;
    n[1] = (a.y - mean) * rstd * g0.y + e0.y;
    n[2] = (a.z - mean) * rstd * g0.z + e0.z;
    n[3] = (a.w - mean) * rstd * g0.w + e0.w;
    n[4] = (b.x - mean) * rstd * g1.x + e1.x;
    n[5] = (b.y - mean) * rstd * g1.y + e1.y;
    n[6] = (b.z - mean) * rstd * g1.z + e1.z;
    n[7] = (b.w - mean) * rstd * g1.w + e1.w;

    ushort4 o0, o1;
    o0.x = f2bf(n[0]); o0.y = f2bf(n[1]); o0.z = f2bf(n[2]); o0.w = f2bf(n[3]);
    o1.x = f2bf(n[4]); o1.y = f2bf(n[5]); o1.z = f2bf(n[6]); o1.w = f2bf(n[7]);
    ((ushort4*)(xn + (size_t)row * D_))[t]       = o0;
    ((ushort4*)(xn + (size_t)row * D_))[t + 256] = o1;
}

// ---------------------------------------------------------------------------
// prep1: 224 blocks total (all resident at once, <1 block/CU)
//   blocks [0,32):    P (DxR f32) -> PT (RxD bf16)  [LDS transpose]
//   blocks [32,160):  C[r][d] = sum_s toep[r-s+127]*Wq[s][d]
//                     128 blocks = 16 r-tiles(16) x 8 d-chunks(256); thread=d;
//                     Wq reads coalesced; zero-padded toep in LDS (no branch)
//   blocks [160,224): scale: 64 blocks x 32 l-rows; wave = 8 rows;
//                     closed-form cos-sum: sin(128a)cos(127.5a)/sin(a/2);
//                     phi_bias row = 1 coalesced float4/lane; feat folded
//                     into the same shfl reduction
// ---------------------------------------------------------------------------
__global__ __launch_bounds__(256) void prep1_kernel(
    const float* __restrict__ P, unsigned short* __restrict__ PT,
    const float* __restrict__ toep, const float* __restrict__ Wq,
    float* __restrict__ C,
    const float* __restrict__ phi_bias, const float* __restrict__ phi_w,
    const float* __restrict__ feat, const float* __restrict__ bq,
    const float* __restrict__ g_logit, const int* __restrict__ step,
    float* __restrict__ gs, float* __restrict__ bgs)
{
    __shared__ __align__(16) char smem[32768];
    const int bid = blockIdx.x;
    const int t   = threadIdx.x;

    if (bid < 32) {
        // ---- PT transpose ----
        unsigned short* sT = (unsigned short*)smem;   // 64*256 ushort = 32 KB
        const int k0 = bid * 64;
#pragma unroll 8
        for (int j = 0; j < 64; j++)
            sT[j * 256 + t] = f2bf(P[(size_t)(k0 + j) * R_ + t]);
        __syncthreads();
#pragma unroll
        for (int c = 0; c < 16; c++) {
            ushort4 v;
            v.x = sT[(c * 4 + 0) * 256 + t];
            v.y = sT[(c * 4 + 1) * 256 + t];
            v.z = sT[(c * 4 + 2) * 256 + t];
            v.w = sT[(c * 4 + 3) * 256 + t];
            *(ushort4*)(PT + (size_t)t * D_ + k0 + c * 4) = v;
        }
    } else if (bid < 160) {
        // ---- C = Toeplitz(toep) x Wq, r-tile 16, branch-free padded toep ----
        float* T2 = (float*)smem;                     // 512 floats
        const int cid = bid - 32;
        const int r0  = (cid >> 3) * 16;
        const int d   = (cid & 7) * 256 + t;
        {
            int j0 = t - 128;                         // T2[t] = toep[t-128]
            T2[t] = ((unsigned)j0 < 255u) ? toep[j0] : 0.f;
            int j1 = t + 128;                         // T2[t+256] = toep[t+128]
            T2[t + 256] = ((unsigned)j1 < 255u) ? toep[j1] : 0.f;
        }
        __syncthreads();
        float acc[16] = {};
#pragma unroll 4
        for (int s = 0; s < 256; s++) {
            float wv = Wq[(size_t)s * D_ + d];        // coalesced across t
            int base = r0 - s + 255;                  // +ri -> T2 index
#pragma unroll
            for (int ri = 0; ri < 16; ri++)
                acc[ri] += T2[base + ri] * wv;        // uniform -> broadcast
        }
#pragma unroll
        for (int ri = 0; ri < 16; ri++)
            C[(size_t)(r0 + ri) * D_ + d] = acc[ri];  // coalesced across t
    } else {
        // ---- scale ----
        float* redp = (float*)smem;                   // 4 floats
        const int l0   = (bid - 160) * 32;
        const int w    = t >> 6, lane = t & 63;
        // block-wide pws = sum(phi_w)
        float pw = phi_w[t];
#pragma unroll
        for (int o = 32; o; o >>= 1) pw += __shfl_down(pw, o);
        if (lane == 0) redp[w] = pw;
        __syncthreads();
        float pws = redp[0] + redp[1] + redp[2] + redp[3];
        float det = fminf((float)step[0] / 2000.0f, 1.0f);
        float fscl = pws * (1.0f / B_);
#pragma unroll
        for (int i = 0; i < 8; i++) {
            int l = l0 + w * 8 + i;
            float4 pv = *(const float4*)(phi_bias + (size_t)l * R_ + lane * 4);
            float val = pv.x + pv.y + pv.z + pv.w;
            if (lane < 8) val += feat[(size_t)lane * L_ + l] * fscl;
#pragma unroll
            for (int o = 32; o; o >>= 1) val += __shfl_down(val, o);
            if (lane == 0) {
                float a  = 3.14159265358979323846f * ((float)l + 0.5f) * (1.0f / L_);
                float cs = sinf(128.0f * a) * cosf(127.5f * a) / sinf(0.5f * a);
                float sc = (det * cs + val) * (1.0f / R_);
                float gl = g_logit[l >> 10];
                float gg = 1.0f / (1.0f + expf(-gl));
                gs[l]  = gg * sc;
                bgs[l] = bq[l] * gg * sc;
            }
        }
    }
}

// ---------------------------------------------------------------------------
// prep2: WT[d][q] = sum_r dlt[r][q] * C[r][d]
// 1024 blocks (no LDS), d0 = bid*2; dlt reads coalesced, C reads uniform.
// ---------------------------------------------------------------------------
__global__ __launch_bounds__(256) void prep2_kernel(
    const float* __restrict__ dlt, const float* __restrict__ C,
    unsigned short* __restrict__ WT)
{
    const int d0 = blockIdx.x * 2;
    const int q  = threadIdx.x;
    float a0 = 0.f, a1 = 0.f;
#pragma unroll 8
    for (int r = 0; r < 256; r++) {
        float dv = dlt[(size_t)r * R_ + q];           // coalesced across q
        const float* cr = C + (size_t)r * D_ + d0;    // uniform -> s_load
        a0 += dv * cr[0];
        a1 += dv * cr[1];
    }
    WT[(size_t)(d0 + 0) * R_ + q] = f2bf(a0);
    WT[(size_t)(d0 + 1) * R_ + q] = f2bf(a1);
}

// ---------------------------------------------------------------------------
// GEMM1 (m97 structure): u(16384x256 bf16) = xn @ P  (B transposed: PT, RxD)
// BM=128, BN=128, BK=64; 4 waves x (64x64) sub-tiles; double-buffered GLDS16
// prefetch-before-compute; 64KB LDS, 2 blocks/CU. grid (2, 128).
// ---------------------------------------------------------------------------
__global__ __launch_bounds__(256, 2) void gemm1_kernel(
    const unsigned short* __restrict__ A,   // xn, lda=2048
    const unsigned short* __restrict__ BT,  // PT,  ldb=2048
    unsigned short* __restrict__ U)         // 16384x256
{
    __shared__ __align__(16) unsigned short sA[2][2][128 * 32];
    __shared__ __align__(16) unsigned short sB[2][2][128 * 32];
    const int tid  = threadIdx.x;
    const int n0   = blockIdx.x * 128;
    const int m0   = blockIdx.y * 128;
    const int w    = tid >> 6, lane = tid & 63;
    const int quad = lane >> 4, m16 = lane & 15;
    const int wm   = (w >> 1) * 64, wn = (w & 1) * 64;
    const int ra   = tid >> 2, sa = tid & 3;

    const unsigned short* apb = A  + (size_t)(m0 + ra) * 2048 + sa * 8;
    const unsigned short* bpb = BT + (size_t)(n0 + ra) * 2048 + sa * 8;

    f32x4 acc[4][4] = {};

#define G1_STAGE(buf, kc)                                                       \
    do {                                                                        \
        _Pragma("unroll")                                                       \
        for (int h = 0; h < 2; h++) {                                           \
            GLDS16(apb + (kc) + h * 32,              &sA[buf][h][tid * 8]);     \
            GLDS16(apb + (kc) + h * 32 + 64 * 2048,  &sA[buf][h][2048 + tid * 8]); \
            GLDS16(bpb + (kc) + h * 32,              &sB[buf][h][tid * 8]);     \
            GLDS16(bpb + (kc) + h * 32 + 64 * 2048,  &sB[buf][h][2048 + tid * 8]); \
        }                                                                       \
    } while (0)

    G1_STAGE(0, 0);
    __syncthreads();

    int cur = 0;
    for (int kc = 0; kc < 2048; kc += 64) {
        if (kc + 64 < 2048) G1_STAGE(cur ^ 1, kc + 64);
#pragma unroll
        for (int h = 0; h < 2; h++) {
            bf16x8 af[4], bf[4];
#pragma unroll
            for (int i = 0; i < 4; i++)
                af[i] = *(const bf16x8*)(&sA[cur][h][(wm + i * 16 + m16) * 32 + quad * 8]);
#pragma unroll
            for (int j = 0; j < 4; j++)
                bf[j] = *(const bf16x8*)(&sB[cur][h][(wn + j * 16 + m16) * 32 + quad * 8]);
#pragma unroll
            for (int i = 0; i < 4; i++)
#pragma unroll
                for (int j = 0; j < 4; j++)
                    acc[i][j] = __builtin_amdgcn_mfma_f32_16x16x32_bf16(
                        af[i], bf[j], acc[i][j], 0, 0, 0);
        }
        __syncthreads();
        cur ^= 1;
    }
#undef G1_STAGE

#pragma unroll
    for (int i = 0; i < 4; i++)
#pragma unroll
        for (int j = 0; j < 4; j++) {
            int col = n0 + wn + j * 16 + m16;
#pragma unroll
            for (int r = 0; r < 4; r++) {
                int row = m0 + wm + i * 16 + quad * 4 + r;
                U[(size_t)row * 256 + col] = f2bf(acc[i][j][r]);
            }
        }
}

// ---------------------------------------------------------------------------
// GEMM2: out(16384x2048 f32) = u @ W_eff (via WT), epilogue *gs[col]+bgs[col]
// BM=128, BN=128, BK=32 (8 K-steps), double-buffered. 32KB LDS, 3 blocks/CU.
// ---------------------------------------------------------------------------
__global__ __launch_bounds__(256, 3) void gemm2_kernel(
    const unsigned short* __restrict__ A,   // u,  lda=256
    const unsigned short* __restrict__ BT,  // WT, ldb=256
    const float* __restrict__ gs, const float* __restrict__ bgs,
    float* __restrict__ out)
{
    __shared__ __align__(16) unsigned short sA[2][128 * 32];
    __shared__ __align__(16) unsigned short sB[2][128 * 32];
    const int tid  = threadIdx.x;
    const int n0   = blockIdx.x * 128;
    const int m0   = blockIdx.y * 128;
    const int w    = tid >> 6, lane = tid & 63;
    const int quad = lane >> 4, m16 = lane & 15;
    const int wm   = (w >> 1) * 64, wn = (w & 1) * 64;
    const int ra   = tid >> 2, sa = tid & 3;

    const unsigned short* apb0 = A  + (size_t)(m0 + ra) * 256 + sa * 8;
    const unsigned short* apb1 = apb0 + (size_t)64 * 256;
    const unsigned short* bpb0 = BT + (size_t)(n0 + ra) * 256 + sa * 8;
    const unsigned short* bpb1 = bpb0 + (size_t)64 * 256;

    float gv[4], bv[4];
#pragma unroll
    for (int j = 0; j < 4; j++) {
        int col = n0 + wn + j * 16 + m16;
        gv[j] = gs[col];
        bv[j] = bgs[col];
    }

    f32x4 acc[4][4] = {};

#define G2_STAGE(buf, kc)                                      \
    do {                                                       \
        GLDS16(apb0 + (kc), &sA[buf][tid * 8]);                \
        GLDS16(apb1 + (kc), &sA[buf][(256 + tid) * 8]);        \
        GLDS16(bpb0 + (kc), &sB[buf][tid * 8]);                \
        GLDS16(bpb1 + (kc), &sB[buf][(256 + tid) * 8]);        \
    } while (0)

    G2_STAGE(0, 0);
    __syncthreads();

    int cur = 0;
    for (int kc = 0; kc < 256; kc += 32) {
        if (kc + 32 < 256) G2_STAGE(cur ^ 1, kc + 32);
        bf16x8 af[4], bf[4];
#pragma unroll
        for (int i = 0; i < 4; i++)
            af[i] = *(const bf16x8*)(&sA[cur][(wm + i * 16 + m16) * 32 + quad * 8]);
#pragma unroll
        for (int j = 0; j < 4; j++)
            bf[j] = *(const bf16x8*)(&sB[cur][(wn + j * 16 + m16) * 32 + quad * 8]);
#pragma unroll
        for (int i = 0; i < 4; i++)
#pragma unroll
            for (int j = 0; j < 4; j++)
                acc[i][j] = __builtin_amdgcn_mfma_f32_16x16x32_bf16(
                    af[i], bf[j], acc[i][j], 0, 0, 0);
        __syncthreads();
        cur ^= 1;
    }
#undef G2_STAGE

#pragma unroll
    for (int i = 0; i < 4; i++)
#pragma unroll
        for (int r = 0; r < 4; r++) {
            int row = m0 + wm + i * 16 + quad * 4 + r;
            float* op = out + (size_t)row * 2048 + n0 + wn;
#pragma unroll
            for (int j = 0; j < 4; j++)
                op[j * 16 + m16] = acc[i][j][r] * gv[j] + bv[j];
        }
}

// ---------------------------------------------------------------------------
extern "C" void kernel_launch(void* const* d_in, const int* in_sizes, int n_in,
                              void* d_out, int out_size, void* d_ws, size_t ws_size,
                              hipStream_t stream)
{
    const float* x        = (const float*)d_in[0];
    const float* ln_gamma = (const float*)d_in[1];
    const float* ln_beta  = (const float*)d_in[2];
    const float* P        = (const float*)d_in[3];
    const float* dlt      = (const float*)d_in[4];
    const float* phi_w    = (const float*)d_in[5];
    const float* phi_bias = (const float*)d_in[6];
    const float* toep     = (const float*)d_in[7];
    const float* Wq       = (const float*)d_in[8];
    const float* bq       = (const float*)d_in[9];
    const float* g_logit  = (const float*)d_in[10];
    const int*   step     = (const int*)d_in[11];
    float* out = (float*)d_out;

    char* w = (char*)d_ws;
    unsigned short* xn  = (unsigned short*)(w);                    // 67,108,864 B
    unsigned short* u   = (unsigned short*)(w + 67108864);         //  8,388,608 B
    unsigned short* PT  = (unsigned short*)(w + 75497472);         //  1,048,576 B
    unsigned short* WT  = (unsigned short*)(w + 76546048);         //  1,048,576 B
    float*          C   = (float*)(w + 77594624);                  //  2,097,152 B
    float*          feat= (float*)(w + 79691776);                  //     65,536 B
    float*          gs  = (float*)(w + 79757312);                  //      8,192 B
    float*          bgs = (float*)(w + 79765504);                  //      8,192 B

    ln_kernel<<<dim3(B_ * L_), dim3(256), 0, stream>>>(x, ln_gamma, ln_beta, xn, feat);
    prep1_kernel<<<dim3(224), dim3(256), 0, stream>>>(P, PT, toep, Wq, C,
                                                      phi_bias, phi_w, feat, bq,
                                                      g_logit, step, gs, bgs);
    prep2_kernel<<<dim3(1024), dim3(256), 0, stream>>>(dlt, C, WT);
    gemm1_kernel<<<dim3(2, 128), dim3(256), 0, stream>>>(xn, PT, u);
    gemm2_kernel<<<dim3(16, 128), dim3(256), 0, stream>>>(u, WT, gs, bgs, out);
}